// Round 5
// baseline (1702.929 us; speedup 1.0000x reference)
//
#include <hip/hip_runtime.h>
#include <limits.h>

// ---------------- problem constants ----------------
constexpr int kB   = 128;   // batch
constexpr int kSin = 50;    // encoder seq len
constexpr int kT   = 25;    // decoder steps
constexpr int kD   = 128;   // feature dim
constexpr int kR   = 2048;  // RNN hidden
constexpr int kNB  = 256;   // grid blocks (1 per CU)
constexpr int kNT  = 512;   // threads per block (8 waves, 2/SIMD)
constexpr int kRing = 8;    // h / inp ring depth (staleness window = 8 steps)

typedef __bf16 bf16x8 __attribute__((ext_vector_type(8)));
typedef float  f32x4  __attribute__((ext_vector_type(4)));
typedef unsigned short u16;
typedef unsigned long long u64;

__device__ __forceinline__ float bf2f(u16 u){ union{unsigned i; float f;}x; x.i=((unsigned)u)<<16; return x.f; }
__device__ __forceinline__ u16 f2bf(float f){ union{float f; unsigned i;}x; x.f=f; return (u16)((x.i + 0x7FFFu + ((x.i>>16)&1u))>>16); }
__device__ __forceinline__ float sigm(float x){ return 1.f/(1.f+__expf(-x)); }
// fast tanh: 1 - 2/(e^{2x}+1). Monotone, correct at +-inf, bf16-accurate.
__device__ __forceinline__ float tanhf_fast(float x){ return 1.f - 2.f/(__expf(2.f*x)+1.f); }

// ---- memory model (v9 = v8 ring + cadenced fences, unchanged) ----
// Cross-block stores: relaxed agent atomics (write-through; MALL canonical;
// no dirty lines -> invalidates safe at any time). h/x/part reads: plain
// cached; staleness prevented by 8-deep rings + acquire fence at GRU steps
// g%8==0 (each ring slot is re-read exactly 8 steps later, with exactly one
// fence in between). Flags stay on the agent-atomic path.
__device__ __forceinline__ void stg32(unsigned* p, unsigned v){
    __hip_atomic_store(p, v, __ATOMIC_RELAXED, __HIP_MEMORY_SCOPE_AGENT);
}
__device__ __forceinline__ void stg64(u64* p, u64 v){
    __hip_atomic_store(p, v, __ATOMIC_RELAXED, __HIP_MEMORY_SCOPE_AGENT);
}
__device__ __forceinline__ unsigned ald32(const void* p){
    return __hip_atomic_load((const unsigned*)p, __ATOMIC_RELAXED, __HIP_MEMORY_SCOPE_AGENT);
}
__device__ __forceinline__ float aldf(const float* p){
    union{ unsigned u; float f; } t; t.u = ald32(p); return t.f;
}

__device__ __forceinline__ bf16x8 pack8(float4 a, float4 b){
    union{ bf16x8 v; u16 u[8]; } t;
    t.u[0]=f2bf(a.x); t.u[1]=f2bf(a.y); t.u[2]=f2bf(a.z); t.u[3]=f2bf(a.w);
    t.u[4]=f2bf(b.x); t.u[5]=f2bf(b.y); t.u[6]=f2bf(b.z); t.u[7]=f2bf(b.w);
    return t.v;
}

// ---- fine-grained producer/consumer sync (kept from v7) ----
__device__ __forceinline__ int pollflag(int* flags, int idx, int iter){
    if ((iter & 31) == 31) return atomicMax(&flags[idx*16], INT_MIN);
    return (int)ald32(&flags[idx*16]);
}
__device__ __forceinline__ void wait16(int* flags, int k, int base){
    const int lane = threadIdx.x & 63;
    for (int iter = 0;; ++iter){
        bool ok = true;
        if (lane < 16) ok = (pollflag(flags, base + lane, iter) >= k);
        if (__ballot(ok) == ~0ull) return;
        __builtin_amdgcn_s_sleep(1);
    }
}
__device__ __forceinline__ void wait128(int* flags, int k, int base){
    const int lane = threadIdx.x & 63;
    for (int iter = 0;; ++iter){
        bool ok = true;
#pragma unroll
        for (int j = 0; j < 2; ++j)
            ok &= (pollflag(flags, base + lane*2 + j, iter) >= k);
        if (__ballot(ok) == ~0ull) return;
        __builtin_amdgcn_s_sleep(1);
    }
}
__device__ __forceinline__ void arrive(int* flags, int k){
    __syncthreads();   // vmcnt(0) before s_barrier: stores at coherence point
    if (threadIdx.x == 0) atomicMax(&flags[blockIdx.x*16], k);
}

// ---- full barrier (init / fc1 boundaries only) ----
__device__ __forceinline__ void gbar(int* flags, int k, int base, int perlane)
{
    __syncthreads();
    const int tid = threadIdx.x;
    if (tid == 0) atomicMax(&flags[blockIdx.x*16], k);
    if (tid < 64) {
        int iter = 0;
        for (;;) {
            bool ok = true;
            for (int j = 0; j < perlane; ++j) {
                const int idx = base + tid*perlane + j;
                int v;
                if ((iter & 31) == 31) v = atomicMax(&flags[idx*16], INT_MIN);
                else                   v = (int)ald32(&flags[idx*16]);
                ok &= (v >= k);
            }
            if (__ballot(ok) == ~0ull) break;
            ++iter;
            __builtin_amdgcn_s_sleep(1);
        }
    }
    __syncthreads();
}

__device__ __forceinline__ void cvt_f32_bf16(const float* __restrict__ s, u16* __restrict__ d,
                                             int n4, int gtid, int gstride)
{
    for (int i = gtid; i < n4; i += gstride) {
        float4 v = ((const float4*)s)[i];
        u64 pk = (u64)f2bf(v.x) | ((u64)f2bf(v.y)<<16) | ((u64)f2bf(v.z)<<32) | ((u64)f2bf(v.w)<<48);
        stg64((u64*)d + i, pk);
    }
}

// ---------------- single-iter GEMM (K=128) for fc1 (NT=8) ----------------
template<int NT, int NACC>
__device__ __forceinline__ void small_gemm(
    const u16* __restrict__ Am, int alda,
    const u16* __restrict__ Bp, int bldb,
    f32x4 (&acc)[NACC], u16* pool)
{
    const int tid=threadIdx.x, lane=tid&63, wv=tid>>6, g=wv>>2, mt=wv&3, ar=lane&15, aq=lane>>4;
    u16* sA = pool;
    u16* sB = pool + 8704;
    { int q=tid,     r=q>>4, c=q&15; *(uint4*)&sA[r*136+c*8] = *(const uint4*)(Am + r*alda + c*8); }
    { int q=tid+512, r=q>>4, c=q&15; *(uint4*)&sA[r*136+c*8] = *(const uint4*)(Am + r*alda + c*8); }
    for (int q=tid; q<NT*256; q+=kNT){
        int r=q>>4, c=q&15;
        *(uint4*)&sB[r*136+c*8] = *(const uint4*)(Bp + (size_t)r*bldb + c*8);
    }
    __syncthreads();
#pragma unroll
    for (int jt=0; jt<NT; ++jt){
        if ((jt&1) != g) continue;
#pragma unroll
        for (int kk=0; kk<4; ++kk){
            bf16x8 a = *(const bf16x8*)&sA[(mt*16+ar)*136 + kk*32 + aq*8];
            bf16x8 b = *(const bf16x8*)&sB[(jt*16+ar)*136 + kk*32 + aq*8];
            acc[jt>>1] = __builtin_amdgcn_mfma_f32_16x16x32_bf16(a,b,acc[jt>>1],0,0,0);
        }
    }
    __syncthreads();
}

// ---------------- GRU step v9: software-pipelined h/x loads ----------------
// Load-latency exposures per step cut from ~6 (4 h-batches + x + drain) to
// ~2.5: issue mt0+mt1 h batches upfront, refill mt2 behind mt0's MFMAs and
// mt3 behind the x section; x loads issued at phase top.
#define MT_MFMA(MT, BUF)                                                            \
    _Pragma("unroll")                                                               \
    for (int c=0; c<8; ++c){                                                        \
        acc[0][MT] = __builtin_amdgcn_mfma_f32_16x16x32_bf16(BUF[c], wB[0][c], acc[0][MT],0,0,0); \
        acc[1][MT] = __builtin_amdgcn_mfma_f32_16x16x32_bf16(BUF[c], wB[1][c], acc[1][MT],0,0,0); \
        acc[2][MT] = __builtin_amdgcn_mfma_f32_16x16x32_bf16(BUF[c], wB[2][c], acc[2][MT],0,0,0); \
    }

__device__ __forceinline__ void gru_phase_flag(
    const u16* __restrict__ hcur, u16* __restrict__ hnxt,
    const u16* __restrict__ xb,
    const bf16x8 (&wB)[3][8], const bf16x8 (&wI)[3],
    const float4 b4, float (&hprev)[4],
    int wgc, int mrow0, u16* smem, u16* sH,
    int* flags, int hk, int xk, int fbase, bool dofence)
{
    const int tid=threadIdx.x, lane=tid&63, w=tid>>6, ar=lane&15, aq=lane>>4;
    const f32x4 zz = {0.f,0.f,0.f,0.f};
    f32x4 acc[3][4] = {{zz,zz,zz,zz},{zz,zz,zz,zz},{zz,zz,zz,zz}};
    f32x4 xn[4] = {zz,zz,zz,zz};

    if (dofence) __builtin_amdgcn_fence(__ATOMIC_ACQUIRE, "agent");

    // wait only for THIS wave's 16 h-producers, then go.
    if (hk) wait16(flags, hk, fbase + 16*w);

#define HPTR(MT,C) ((const bf16x8*)(hcur + ((((16*w + 2*(C) + (aq>>1))*128 + mrow0 + (MT)*16 + ar)<<4) + (aq&1)*8)))
    bf16x8 af0[8], af1[8];
#pragma unroll
    for (int c=0;c<8;++c) af0[c] = *HPTR(0,c);
#pragma unroll
    for (int c=0;c<8;++c) af1[c] = *HPTR(1,c);

    bf16x8 ax[4];
    if (w < 4){
        if (xk) wait128(flags, xk, fbase);   // h loads already in flight above
#pragma unroll
        for (int mt=0; mt<4; ++mt)
            ax[mt] = *(const bf16x8*)(xb + (mrow0+mt*16+ar)*kD + 32*w + aq*8);
    }

    MT_MFMA(0, af0)
#pragma unroll
    for (int c=0;c<8;++c) af0[c] = *HPTR(2,c);   // refill behind mt0 MFMAs
    MT_MFMA(1, af1)
    if (w < 4){                                   // ax landed behind mt0/mt1
#pragma unroll
        for (int mt=0; mt<4; ++mt){
            acc[0][mt] = __builtin_amdgcn_mfma_f32_16x16x32_bf16(ax[mt], wI[0], acc[0][mt],0,0,0);
            acc[1][mt] = __builtin_amdgcn_mfma_f32_16x16x32_bf16(ax[mt], wI[1], acc[1][mt],0,0,0);
            xn[mt]     = __builtin_amdgcn_mfma_f32_16x16x32_bf16(ax[mt], wI[2], xn[mt],0,0,0);
        }
    }
#pragma unroll
    for (int c=0;c<8;++c) af1[c] = *HPTR(3,c);   // refill behind x section
    MT_MFMA(2, af0)
    MT_MFMA(3, af1)
#undef HPTR

    float* red = (float*)smem;
#define RCELL(wp,g4,mt) (red + (((((wp)*4+(g4))*4+(mt))*64 + lane)<<2))
    if (w >= 4){
#pragma unroll
        for (int g=0; g<3; ++g)
#pragma unroll
            for (int mt=0; mt<4; ++mt)
                *(f32x4*)RCELL(w-4, g, mt) = acc[g][mt];
    }
    __syncthreads();
    if (w < 4){
#pragma unroll
        for (int g=0; g<3; ++g)
#pragma unroll
            for (int mt=0; mt<4; ++mt)
                acc[g][mt] += *(f32x4*)RCELL(w, g, mt);
#pragma unroll
        for (int g=0; g<3; ++g)
#pragma unroll
            for (int mt=0; mt<4; ++mt)
                *(f32x4*)RCELL(w, g, mt) = acc[g][mt];
#pragma unroll
        for (int mt=0; mt<4; ++mt)
            *(f32x4*)RCELL(w, 3, mt) = xn[mt];
    }
    __syncthreads();
    if (tid < 256){
        const int mt = tid>>6, ls = tid&63, aqs = ls>>4, ars = ls&15;
        f32x4 R=zz, Z=zz, NH=zz, NX=zz;
#pragma unroll
        for (int wp=0; wp<4; ++wp){
            R  += *(f32x4*)(red + ((((wp*4+0)*4+mt)*64 + ls)<<2));
            Z  += *(f32x4*)(red + ((((wp*4+1)*4+mt)*64 + ls)<<2));
            NH += *(f32x4*)(red + ((((wp*4+2)*4+mt)*64 + ls)<<2));
            NX += *(f32x4*)(red + ((((wp*4+3)*4+mt)*64 + ls)<<2));
        }
#pragma unroll
        for (int rr=0; rr<4; ++rr){
            const int m = mrow0 + mt*16 + aqs*4 + rr;   // C/D: row=(lane>>4)*4+reg, col=lane&15
            float r_ = sigm(R[rr] + b4.x);
            float z_ = sigm(Z[rr] + b4.y);
            float n_ = tanhf_fast(NX[rr] + b4.z + r_*(NH[rr] + b4.w));
            float hn = (1.f-z_)*n_ + z_*hprev[rr];
            hprev[rr] = hn;
            u16 hb = f2bf(hn);
            sH[(mt*16 + aqs*4 + rr)*16 + ars] = hb;     // LDS for fused fc2 partial
            unsigned other = (unsigned)__shfl_xor((int)(unsigned)hb, 1);
            if (!(ars&1))
                stg32((unsigned*)(hnxt + ((wgc*128+m)<<4) + ars), (unsigned)hb | (other<<16));
        }
    }
#undef RCELL
    __syncthreads();
}

// ---------------- fused fc2 partial: own h'-slice (K=16, zero-padded) ----------------
// wF2 no longer register-resident: reloaded per phase (L2-hot, off the
// recurrence-critical registers). part[mh][row 64][slice 128][col 128] f32
__device__ __forceinline__ void fc2_partial(
    const u16* __restrict__ sH, const u16* __restrict__ WF2,
    int wgc, int mh, float* __restrict__ part)
{
    const int tid=threadIdx.x, lane=tid&63, w=tid>>6, ar=lane&15, aq=lane>>4;
    const int mt = w&3, nh = w>>2;
    bf16x8 a, wj[4];
    if (aq < 2){
        a = *(const bf16x8*)&sH[(mt*16+ar)*16 + aq*8];
#pragma unroll
        for (int j=0;j<4;++j)
            wj[j] = *(const bf16x8*)(WF2 + (size_t)((nh*4+j)*16+ar)*kR + wgc*16 + aq*8);
    } else {
#pragma unroll
        for (int i=0;i<8;++i) a[i] = (__bf16)0.f;
#pragma unroll
        for (int j=0;j<4;++j)
#pragma unroll
            for (int i=0;i<8;++i) wj[j][i] = (__bf16)0.f;
    }
    const f32x4 zz = {0.f,0.f,0.f,0.f};
    f32x4 acc[4] = {zz,zz,zz,zz};
#pragma unroll
    for (int j=0;j<4;++j)
        acc[j] = __builtin_amdgcn_mfma_f32_16x16x32_bf16(a, wj[j], acc[j],0,0,0);
#pragma unroll
    for (int j=0;j<4;++j){
        const int col = (nh*4+j)*16 + ar;
#pragma unroll
        for (int rr=0;rr<4;++rr){
            const int row = mt*16 + aq*4 + rr;
            stg32((unsigned*)(part + ((((size_t)mh*64+row)*128 + wgc)*128 + col)),
                  __float_as_uint(acc[j][rr]));
        }
    }
}

// ---------------- the whole model, one persistent kernel ----------------
__global__ __launch_bounds__(kNT, 2) void seq2seq_kernel(
    const void* __restrict__ enc_in_raw, const void* __restrict__ fc1_w_raw,
    const void* __restrict__ fc1_b_raw,  const void* __restrict__ w_ih_raw,
    const void* __restrict__ w_hh_raw,   const void* __restrict__ b_ih_raw,
    const void* __restrict__ b_hh_raw,   const void* __restrict__ fc2_w_raw,
    const void* __restrict__ fc2_b_raw,
    void* __restrict__ out_raw,
    u16* __restrict__ enc_act,           // [50][128][128] bf16
    u16* __restrict__ h_b16,             // kRing x slice-major [128][128][16] bf16
    u16* __restrict__ inp_b16,           // kRing x [128][128] bf16
    float* __restrict__ inp_f32,         // kRing x [128][128] f32
    float* __restrict__ encF,            // [128][128] f32
    float* __restrict__ bias,            // 6*kR + 2*kD f32
    float* __restrict__ part,            // [2][64][128][128] f32 = 8 MB
    int* flags,
    u16* __restrict__ cv_encx, u16* __restrict__ cv_fc2, u16* __restrict__ cv_fc1)
{
    // 86 KB: deliberately > 80 KB so at most ONE block fits per CU (kills any
    // possibility of 2-blocks-packed-per-CU leaving half the CUs idle).
    __shared__ __align__(16) u16 smem[43008];
    __shared__ int sflag;
    u16* sH = smem + 32768;
    const int wg = blockIdx.x, tid = threadIdx.x;
    const int wgc = wg & 127, mrow0 = (wg >> 7) * 64;
    const int lane = tid & 63, wv = tid >> 6, ar = lane & 15, aq = lane >> 4;
    const int gtid = wg * kNT + tid, gstride = kNB * kNT;
    const int dom = (wg >> 7) * 128;            // flag domain base (row half)
    const size_t HS = (size_t)kB*kR;            // u16 elems per h ring slot

    // ---- dtype detect: f32-as-bf16 shows Inf/NaN bit patterns in low halves ----
    {
        const u16* p = (const u16*)enc_in_raw;
        int found = 0;
        for (int i = tid; i < 16384; i += kNT) found |= ((p[i] & 0x7F80) == 0x7F80) ? 1 : 0;
        if (tid == 0) sflag = 0;
        __syncthreads();
        if (found) sflag = 1;
        __syncthreads();
    }
    const bool F32 = (sflag != 0);

    // ---- register-resident recurrent weights (persist all 74 steps) ----
    bf16x8 wB[3][8];   // w_hh[gate][k-chunk]: wave wv covers k in [256*wv,+256)
    bf16x8 wI[3];      // w_ih[gate]: wave wv<4 covers k-chunk 32*wv
    {
        const int w4 = wv & 3;
        if (F32){
            const float* Wh = (const float*)w_hh_raw;
            const float* Wi = (const float*)w_ih_raw;
#pragma unroll
            for (int g=0; g<3; ++g)
#pragma unroll
                for (int c=0; c<8; ++c){
                    size_t o = (size_t)(g*kR + wgc*16 + ar)*kR + 256*wv + 32*c + aq*8;
                    wB[g][c] = pack8(*(const float4*)(Wh+o), *(const float4*)(Wh+o+4));
                }
#pragma unroll
            for (int g=0; g<3; ++g){
                size_t o = (size_t)(g*kR + wgc*16 + ar)*kD + 32*w4 + aq*8;
                wI[g] = pack8(*(const float4*)(Wi+o), *(const float4*)(Wi+o+4));
            }
        } else {
            const u16* Wh = (const u16*)w_hh_raw;
            const u16* Wi = (const u16*)w_ih_raw;
#pragma unroll
            for (int g=0; g<3; ++g)
#pragma unroll
                for (int c=0; c<8; ++c)
                    wB[g][c] = *(const bf16x8*)(Wh + (size_t)(g*kR + wgc*16 + ar)*kR + 256*wv + 32*c + aq*8);
#pragma unroll
            for (int g=0; g<3; ++g)
                wI[g] = *(const bf16x8*)(Wi + (size_t)(g*kR + wgc*16 + ar)*kD + 32*w4 + aq*8);
        }
    }

    // ---- init: conversions + bias + zero h slot 0, all via coherent stores ----
    if (F32) {
        cvt_f32_bf16((const float*)fc2_w_raw, cv_fc2,  (kD*kR)/4,       gtid, gstride);
        cvt_f32_bf16((const float*)fc1_w_raw, cv_fc1,  (kD*kD)/4,       gtid, gstride);
        cvt_f32_bf16((const float*)enc_in_raw,cv_encx, (kB*kSin*kD)/4,  gtid, gstride);
        for (int i = gtid; i < 3*kR; i += gstride) {
            stg32((unsigned*)&bias[i],        __float_as_uint(((const float*)b_ih_raw)[i]));
            stg32((unsigned*)&bias[3*kR + i], __float_as_uint(((const float*)b_hh_raw)[i]));
        }
        for (int i = gtid; i < kD; i += gstride) {
            stg32((unsigned*)&bias[6*kR + i],      __float_as_uint(((const float*)fc1_b_raw)[i]));
            stg32((unsigned*)&bias[6*kR + kD + i], __float_as_uint(((const float*)fc2_b_raw)[i]));
        }
    } else {
        for (int i = gtid; i < 3*kR; i += gstride) {
            stg32((unsigned*)&bias[i],        __float_as_uint(bf2f(((const u16*)b_ih_raw)[i])));
            stg32((unsigned*)&bias[3*kR + i], __float_as_uint(bf2f(((const u16*)b_hh_raw)[i])));
        }
        for (int i = gtid; i < kD; i += gstride) {
            stg32((unsigned*)&bias[6*kR + i],      __float_as_uint(bf2f(((const u16*)fc1_b_raw)[i])));
            stg32((unsigned*)&bias[6*kR + kD + i], __float_as_uint(bf2f(((const u16*)fc2_b_raw)[i])));
        }
    }
    for (int i = gtid; i < (int)((kB*kR)/2); i += gstride) stg32((unsigned*)h_b16 + i, 0u);
    gbar(flags, 1, 0, 4);                // tok 1: global barrier (256 flags)

    const u16* ENCX = F32 ? cv_encx : (const u16*)enc_in_raw;
    const u16* WF2  = F32 ? cv_fc2  : (const u16*)fc2_w_raw;
    const u16* WF1  = F32 ? cv_fc1  : (const u16*)fc1_w_raw;

    // ---- per-thread constant preloads (first-touch after global barrier) ----
    float4 b4;   // gate biases for this thread's (hc)
    {
        const int hc = wgc*16 + ar;
        b4.x = aldf(&bias[hc])      + aldf(&bias[3*kR+hc]);
        b4.y = aldf(&bias[kR+hc])   + aldf(&bias[4*kR+hc]);
        b4.z = aldf(&bias[2*kR+hc]);
        b4.w = aldf(&bias[5*kR+hc]);
    }
    const float fc2b = aldf(&bias[6*kR + kD + (wg&1)*64 + (tid&63)]);
    float hprev[4] = {0.f, 0.f, 0.f, 0.f};

    // ---- fc1: blocks wgc<50 handle t=wgc ----
    if (wgc < kSin) {
        const int g = wv>>2, mt = wv&3;
        const f32x4 zz = {0.f,0.f,0.f,0.f};
        f32x4 ae[4] = {zz,zz,zz,zz};
        small_gemm<8,4>(ENCX + ((size_t)mrow0*kSin + wgc)*kD, kSin*kD, WF1, kD, ae, smem);
#pragma unroll
        for (int jt=0; jt<8; ++jt){
            if ((jt&1) != g) continue;
            int col = jt*16 + ar;
            float fb = aldf(&bias[6*kR + col]);
#pragma unroll
            for (int rr=0; rr<4; ++rr){
                int m = mrow0 + mt*16 + aq*4 + rr;
                float v = ae[jt>>1][rr] + fb;
                u16 hb = f2bf(v);
                unsigned other = (unsigned)__shfl_xor((int)(unsigned)hb, 1);
                if (!(ar&1))
                    stg32((unsigned*)(enc_act + ((size_t)wgc*kB + m)*kD + col),
                          (unsigned)hb | (other<<16));
                if (wgc == kSin-1)
                    stg32((unsigned*)(encF + (size_t)m*kD + col), __float_as_uint(v));
            }
        }
    }
    gbar(flags, 2, dom, 2);              // tok 2: half-domain barrier

    // ---- encoder: 49 GRU steps, flag-paced; h ring slot = g%8 ----
    for (int t = 0; t < kSin-1; ++t) {
        gru_phase_flag(h_b16 + (size_t)(t & 7)*HS, h_b16 + (size_t)((t+1) & 7)*HS,
                       enc_act + (size_t)t*kB*kD, wB, wI, b4, hprev, wgc, mrow0, smem, sH,
                       flags, (t==0 ? 0 : t+2), 0, dom,
                       (t > 0) && ((t & 7) == 0));
        arrive(flags, t+3);              // A_enc_t token = t+3 (A_48 -> 51)
    }

    // ---- decoder: 25 steps; gru-step g = 49+d; h slot g%8, inp slot d%8 ----
    const u16*   ib  = enc_act + (size_t)(kSin-1)*kB*kD;
    const float* ifp = encF;
    const int mh = wg >> 7;
    for (int d = 0; d < kT; ++d) {
        const int g = 49 + d;
        // phase A: GRU + own-slice fc2 partial (fused)
        gru_phase_flag(h_b16 + (size_t)(g & 7)*HS, h_b16 + (size_t)((g+1) & 7)*HS,
                       ib, wB, wI, b4, hprev, wgc, mrow0, smem, sH,
                       flags, (d==0 ? 51 : 50+2*d), (d==0 ? 0 : 51+2*d), dom,
                       (g & 7) == 0);
        fc2_partial(sH, WF2, wgc, mh, part);
        arrive(flags, 52+2*d);           // A_dec_d token

        // phase B: reduce 128 slice-partials -> out + next x
        u16*   nib = inp_b16 + (size_t)(d & 7)*kB*kD;
        float* nif = inp_f32 + (size_t)(d & 7)*kB*kD;
        wait128(flags, 52+2*d, dom);     // all waves: wait this half's A_d partials
        {
            const int row = wg >> 1, ch = wg & 1;
            const int mh2 = row >> 6, rl = row & 63;
            const float* pr = part + (size_t)((mh2*64 + rl)*128)*128;
            const int cl = tid & 63, sg = tid >> 6;
            float s = 0.f;
#pragma unroll
            for (int j=0;j<16;++j) s += aldf(&pr[(size_t)(sg*16+j)*128 + ch*64 + cl]);
            float* red2 = (float*)smem;
            red2[sg*64 + cl] = s;
            __syncthreads();
            if (tid < 64){
                float t2 = 0.f;
#pragma unroll
                for (int g2=0; g2<8; ++g2) t2 += red2[g2*64 + tid];
                const int colg = ch*64 + tid;
                const float o = t2 + fc2b + ifp[(size_t)row*kD + colg];
                const size_t ob = ((size_t)row*kT + d)*kD + colg;
                if (F32) ((float*)out_raw)[ob] = o;
                else     ((u16*)out_raw)[ob]   = f2bf(o);
                stg32((unsigned*)(nif + (size_t)row*kD + colg), __float_as_uint(o));
                u16 hb = f2bf(o);
                unsigned other = (unsigned)__shfl_xor((int)(unsigned)hb, 1);
                if (!(tid&1))
                    stg32((unsigned*)(nib + (size_t)row*kD + colg), (unsigned)hb | (other<<16));
            }
        }
        arrive(flags, 53+2*d);           // B_dec_d token
        ib = nib; ifp = nif;
    }
}

// ---------------- host launcher ----------------
extern "C" void kernel_launch(void* const* d_in, const int* in_sizes, int n_in,
                              void* d_out, int out_size, void* d_ws, size_t ws_size,
                              hipStream_t stream)
{
    size_t off = 0;
    char* ws = (char*)d_ws;
    auto alloc = [&](size_t bytes) -> char* {
        char* p = ws + off;
        off = (off + bytes + 255) & ~(size_t)255;
        return p;
    };
    u16*   enc_act = (u16*)alloc((size_t)kSin*kB*kD*2);
    u16*   h_b16   = (u16*)alloc((size_t)kRing*kB*kR*2);         // 4 MB ring
    u16*   inp_b16 = (u16*)alloc((size_t)kRing*kB*kD*2);
    float* inp_f32 = (float*)alloc((size_t)kRing*kB*kD*4);
    float* encF    = (float*)alloc((size_t)kB*kD*4);
    float* bias    = (float*)alloc((size_t)(6*kR + 2*kD)*4);
    float* part    = (float*)alloc((size_t)2*64*128*128*4);      // 8 MB
    int*   flags   = (int*)alloc((size_t)kNB*16*4);              // 1 flag / 64B line
    u16*   cv_encx = (u16*)alloc((size_t)kB*kSin*kD*2);
    u16*   cv_fc2  = (u16*)alloc((size_t)kD*kR*2);
    u16*   cv_fc1  = (u16*)alloc((size_t)kD*kD*2);
    (void)ws_size; (void)in_sizes; (void)n_in; (void)out_size;

    seq2seq_kernel<<<dim3(kNB), dim3(kNT), 0, stream>>>(
        d_in[0], d_in[2], d_in[3], d_in[4], d_in[5], d_in[6], d_in[7], d_in[8], d_in[9],
        d_out,
        enc_act, h_b16, inp_b16, inp_f32, encF, bias, part, flags,
        cv_encx, cv_fc2, cv_fc1);
}

// Round 7
// 1517.634 us; speedup vs baseline: 1.1221x; 1.1221x over previous
//
#include <hip/hip_runtime.h>
#include <limits.h>

// ---------------- problem constants ----------------
constexpr int kB   = 128;   // batch
constexpr int kSin = 50;    // encoder seq len
constexpr int kT   = 25;    // decoder steps
constexpr int kD   = 128;   // feature dim
constexpr int kR   = 2048;  // RNN hidden
constexpr int kNB  = 256;   // grid blocks (1 per CU)
constexpr int kNT  = 512;   // threads per block (8 waves, 2/SIMD)
constexpr int kRing = 8;    // h / inp ring depth (staleness window = 8 steps)

typedef __bf16 bf16x8 __attribute__((ext_vector_type(8)));
typedef float  f32x4  __attribute__((ext_vector_type(4)));
typedef unsigned short u16;
typedef unsigned long long u64;

__device__ __forceinline__ float bf2f(u16 u){ union{unsigned i; float f;}x; x.i=((unsigned)u)<<16; return x.f; }
__device__ __forceinline__ u16 f2bf(float f){ union{float f; unsigned i;}x; x.f=f; return (u16)((x.i + 0x7FFFu + ((x.i>>16)&1u))>>16); }
__device__ __forceinline__ float sigm(float x){ return 1.f/(1.f+__expf(-x)); }
// fast tanh: 1 - 2/(e^{2x}+1). Monotone, correct at +-inf, bf16-accurate.
__device__ __forceinline__ float tanhf_fast(float x){ return 1.f - 2.f/(__expf(2.f*x)+1.f); }

// ---- memory model (v10 = v8 ring + cadenced fences; flag path de-contended) ----
// Cross-block stores: relaxed agent atomics (write-through; MALL canonical;
// no dirty lines -> invalidates safe at any time). h/x reads: plain cached;
// staleness prevented by 8-deep rings + acquire fence at GRU steps g%8==0.
// FLAG PATH (this round's change): producer flag-set is a plain agent STORE
// (monotone tokens; same store path + vmcnt-drain ordering as the data
// stores). Poll loops back off with s_sleep(4) and the RMW liveness
// fallback fires only every 4096 iters -- the r5 counters showed FETCH_SIZE
// dominated by poll traffic, i.e. the 128 flag lines were saturated with
// loads + periodic RMW storms, queueing the producer's critical flag-set.
__device__ __forceinline__ void stg32(unsigned* p, unsigned v){
    __hip_atomic_store(p, v, __ATOMIC_RELAXED, __HIP_MEMORY_SCOPE_AGENT);
}
__device__ __forceinline__ void stg64(u64* p, u64 v){
    __hip_atomic_store(p, v, __ATOMIC_RELAXED, __HIP_MEMORY_SCOPE_AGENT);
}
__device__ __forceinline__ unsigned ald32(const void* p){
    return __hip_atomic_load((const unsigned*)p, __ATOMIC_RELAXED, __HIP_MEMORY_SCOPE_AGENT);
}
__device__ __forceinline__ u64 ald64(const void* p){
    return __hip_atomic_load((const u64*)p, __ATOMIC_RELAXED, __HIP_MEMORY_SCOPE_AGENT);
}
__device__ __forceinline__ bf16x8 ald128bf(const u16* p){
    union{ u64 q[2]; bf16x8 v; } t;
    t.q[0] = ald64(p);
    t.q[1] = ald64(p + 4);
    return t.v;
}
__device__ __forceinline__ float aldf(const float* p){
    union{ unsigned u; float f; } t; t.u = ald32(p); return t.f;
}

__device__ __forceinline__ bf16x8 pack8(float4 a, float4 b){
    union{ bf16x8 v; u16 u[8]; } t;
    t.u[0]=f2bf(a.x); t.u[1]=f2bf(a.y); t.u[2]=f2bf(a.z); t.u[3]=f2bf(a.w);
    t.u[4]=f2bf(b.x); t.u[5]=f2bf(b.y); t.u[6]=f2bf(b.z); t.u[7]=f2bf(b.w);
    return t.v;
}

// ---- fine-grained producer/consumer sync (v10) ----
__device__ __forceinline__ int pollflag(int* flags, int idx, int iter){
    if ((iter & 4095) == 4095) return atomicMax(&flags[idx*16], INT_MIN); // rare liveness insurance
    return (int)ald32(&flags[idx*16]);
}
__device__ __forceinline__ void wait16(int* flags, int k, int base){
    const int lane = threadIdx.x & 63;
    for (int iter = 0;; ++iter){
        bool ok = true;
        if (lane < 16) ok = (pollflag(flags, base + lane, iter) >= k);
        if (__ballot(ok) == ~0ull) return;
        __builtin_amdgcn_s_sleep(4);
    }
}
__device__ __forceinline__ void wait128(int* flags, int k, int base){
    const int lane = threadIdx.x & 63;
    for (int iter = 0;; ++iter){
        bool ok = true;
#pragma unroll
        for (int j = 0; j < 2; ++j)
            ok &= (pollflag(flags, base + lane*2 + j, iter) >= k);
        if (__ballot(ok) == ~0ull) return;
        __builtin_amdgcn_s_sleep(4);
    }
}
// arrive: barrier (drains each wave's stores to the coherence point) then a
// PLAIN agent store of the token (monotone; no RMW -> no MALL queueing).
__device__ __forceinline__ void arrive(int* flags, int k){
    __syncthreads();
    if (threadIdx.x == 0) stg32((unsigned*)&flags[blockIdx.x*16], (unsigned)k);
}

// ---- full barrier (init / fc1 boundaries only) ----
__device__ __forceinline__ void gbar(int* flags, int k, int base, int perlane)
{
    __syncthreads();
    const int tid = threadIdx.x;
    if (tid == 0) atomicMax(&flags[blockIdx.x*16], k);
    if (tid < 64) {
        int iter = 0;
        for (;;) {
            bool ok = true;
            for (int j = 0; j < perlane; ++j) {
                const int idx = base + tid*perlane + j;
                int v;
                if ((iter & 511) == 511) v = atomicMax(&flags[idx*16], INT_MIN);
                else                     v = (int)ald32(&flags[idx*16]);
                ok &= (v >= k);
            }
            if (__ballot(ok) == ~0ull) break;
            ++iter;
            __builtin_amdgcn_s_sleep(2);
        }
    }
    __syncthreads();
}

__device__ __forceinline__ void cvt_f32_bf16(const float* __restrict__ s, u16* __restrict__ d,
                                             int n4, int gtid, int gstride)
{
    for (int i = gtid; i < n4; i += gstride) {
        float4 v = ((const float4*)s)[i];
        u64 pk = (u64)f2bf(v.x) | ((u64)f2bf(v.y)<<16) | ((u64)f2bf(v.z)<<32) | ((u64)f2bf(v.w)<<48);
        stg64((u64*)d + i, pk);
    }
}

// ---------------- single-iter GEMM (K=128) for fc1 (NT=8) ----------------
template<int NT, int NACC>
__device__ __forceinline__ void small_gemm(
    const u16* __restrict__ Am, int alda,
    const u16* __restrict__ Bp, int bldb,
    f32x4 (&acc)[NACC], u16* pool)
{
    const int tid=threadIdx.x, lane=tid&63, wv=tid>>6, g=wv>>2, mt=wv&3, ar=lane&15, aq=lane>>4;
    u16* sA = pool;
    u16* sB = pool + 8704;
    { int q=tid,     r=q>>4, c=q&15; *(uint4*)&sA[r*136+c*8] = *(const uint4*)(Am + r*alda + c*8); }
    { int q=tid+512, r=q>>4, c=q&15; *(uint4*)&sA[r*136+c*8] = *(const uint4*)(Am + r*alda + c*8); }
    for (int q=tid; q<NT*256; q+=kNT){
        int r=q>>4, c=q&15;
        *(uint4*)&sB[r*136+c*8] = *(const uint4*)(Bp + (size_t)r*bldb + c*8);
    }
    __syncthreads();
#pragma unroll
    for (int jt=0; jt<NT; ++jt){
        if ((jt&1) != g) continue;
#pragma unroll
        for (int kk=0; kk<4; ++kk){
            bf16x8 a = *(const bf16x8*)&sA[(mt*16+ar)*136 + kk*32 + aq*8];
            bf16x8 b = *(const bf16x8*)&sB[(jt*16+ar)*136 + kk*32 + aq*8];
            acc[jt>>1] = __builtin_amdgcn_mfma_f32_16x16x32_bf16(a,b,acc[jt>>1],0,0,0);
        }
    }
    __syncthreads();
}

// ---------------- GRU step (R4 body) + in-barrier h-flag publication ----------------
// setk: token published right after the final barrier (h' is at the
// coherence point by then: every wave's stores drained before the barrier).
__device__ __forceinline__ void gru_phase_flag(
    const u16* __restrict__ hcur, u16* __restrict__ hnxt,
    const u16* __restrict__ xb,
    const bf16x8 (&wB)[3][8], const bf16x8 (&wI)[3],
    const float4 b4, float (&hprev)[4],
    int wgc, int mrow0, u16* smem, u16* sH,
    int* flags, int hk, int xk, int fbase, bool dofence, int setk)
{
    const int tid=threadIdx.x, lane=tid&63, w=tid>>6, ar=lane&15, aq=lane>>4;
    const f32x4 zz = {0.f,0.f,0.f,0.f};
    f32x4 acc[3][4] = {{zz,zz,zz,zz},{zz,zz,zz,zz},{zz,zz,zz,zz}};
    f32x4 xn[4] = {zz,zz,zz,zz};

    if (dofence) __builtin_amdgcn_fence(__ATOMIC_ACQUIRE, "agent");

    // wait only for THIS wave's 16 h-producers, then go.
    if (hk) wait16(flags, hk, fbase + 16*w);

#pragma unroll
    for (int mt=0; mt<4; ++mt){
        const int row = mrow0 + mt*16 + ar;
        bf16x8 af[8];
#pragma unroll
        for (int c=0; c<8; ++c){
            const int s = 16*w + 2*c + (aq>>1);
            af[c] = *(const bf16x8*)(hcur + (((s*128 + row)<<4) + (aq&1)*8));
        }
#pragma unroll
        for (int c=0; c<8; ++c){
            acc[0][mt] = __builtin_amdgcn_mfma_f32_16x16x32_bf16(af[c], wB[0][c], acc[0][mt],0,0,0);
            acc[1][mt] = __builtin_amdgcn_mfma_f32_16x16x32_bf16(af[c], wB[1][c], acc[1][mt],0,0,0);
            acc[2][mt] = __builtin_amdgcn_mfma_f32_16x16x32_bf16(af[c], wB[2][c], acc[2][mt],0,0,0);
        }
    }
    if (w < 4){
        // inp wait overlapped behind the hh-MFMAs above
        if (xk) wait128(flags, xk, fbase);
#pragma unroll
        for (int mt=0; mt<4; ++mt){
            bf16x8 ax = *(const bf16x8*)(xb + (mrow0+mt*16+ar)*kD + 32*w + aq*8);
            acc[0][mt] = __builtin_amdgcn_mfma_f32_16x16x32_bf16(ax, wI[0], acc[0][mt],0,0,0);
            acc[1][mt] = __builtin_amdgcn_mfma_f32_16x16x32_bf16(ax, wI[1], acc[1][mt],0,0,0);
            xn[mt]     = __builtin_amdgcn_mfma_f32_16x16x32_bf16(ax, wI[2], xn[mt],0,0,0);
        }
    }
    float* red = (float*)smem;
#define RCELL(wp,g4,mt) (red + (((((wp)*4+(g4))*4+(mt))*64 + lane)<<2))
    if (w >= 4){
#pragma unroll
        for (int g=0; g<3; ++g)
#pragma unroll
            for (int mt=0; mt<4; ++mt)
                *(f32x4*)RCELL(w-4, g, mt) = acc[g][mt];
    }
    __syncthreads();
    if (w < 4){
#pragma unroll
        for (int g=0; g<3; ++g)
#pragma unroll
            for (int mt=0; mt<4; ++mt)
                acc[g][mt] += *(f32x4*)RCELL(w, g, mt);
#pragma unroll
        for (int g=0; g<3; ++g)
#pragma unroll
            for (int mt=0; mt<4; ++mt)
                *(f32x4*)RCELL(w, g, mt) = acc[g][mt];
#pragma unroll
        for (int mt=0; mt<4; ++mt)
            *(f32x4*)RCELL(w, 3, mt) = xn[mt];
    }
    __syncthreads();
    if (tid < 256){
        const int mt = tid>>6, ls = tid&63, aqs = ls>>4, ars = ls&15;
        f32x4 R=zz, Z=zz, NH=zz, NX=zz;
#pragma unroll
        for (int wp=0; wp<4; ++wp){
            R  += *(f32x4*)(red + ((((wp*4+0)*4+mt)*64 + ls)<<2));
            Z  += *(f32x4*)(red + ((((wp*4+1)*4+mt)*64 + ls)<<2));
            NH += *(f32x4*)(red + ((((wp*4+2)*4+mt)*64 + ls)<<2));
            NX += *(f32x4*)(red + ((((wp*4+3)*4+mt)*64 + ls)<<2));
        }
#pragma unroll
        for (int rr=0; rr<4; ++rr){
            const int m = mrow0 + mt*16 + aqs*4 + rr;   // C/D: row=(lane>>4)*4+reg, col=lane&15
            float r_ = sigm(R[rr] + b4.x);
            float z_ = sigm(Z[rr] + b4.y);
            float n_ = tanhf_fast(NX[rr] + b4.z + r_*(NH[rr] + b4.w));
            float hn = (1.f-z_)*n_ + z_*hprev[rr];
            hprev[rr] = hn;
            u16 hb = f2bf(hn);
            sH[(mt*16 + aqs*4 + rr)*16 + ars] = hb;     // LDS for fused fc2 partial
            unsigned other = (unsigned)__shfl_xor((int)(unsigned)hb, 1);
            if (!(ars&1))
                stg32((unsigned*)(hnxt + ((wgc*128+m)<<4) + ars), (unsigned)hb | (other<<16));
        }
    }
#undef RCELL
    __syncthreads();
    // h' published here: all waves' stores are past the coherence point
    // (per-wave vmcnt(0) before the barrier above). Plain store, no RMW.
    if (setk && tid == 0) stg32((unsigned*)&flags[blockIdx.x*16], (unsigned)setk);
}

// ---------------- fused fc2 partial: own h'-slice (K=16, zero-padded) ----------------
// part layout: part[mh][row 64][slice 128][col 128] f32
__device__ __forceinline__ void fc2_partial(
    const u16* __restrict__ sH, const bf16x8 (&wF2)[4],
    int wgc, int mh, float* __restrict__ part)
{
    const int tid=threadIdx.x, lane=tid&63, w=tid>>6, ar=lane&15, aq=lane>>4;
    const int mt = w&3, nh = w>>2;
    bf16x8 a;
    if (aq < 2) a = *(const bf16x8*)&sH[(mt*16+ar)*16 + aq*8];
    else {
#pragma unroll
        for (int i=0;i<8;++i) a[i] = (__bf16)0.f;
    }
    const f32x4 zz = {0.f,0.f,0.f,0.f};
    f32x4 acc[4] = {zz,zz,zz,zz};
#pragma unroll
    for (int j=0;j<4;++j)
        acc[j] = __builtin_amdgcn_mfma_f32_16x16x32_bf16(a, wF2[j], acc[j],0,0,0);
#pragma unroll
    for (int j=0;j<4;++j){
        const int col = (nh*4+j)*16 + ar;
#pragma unroll
        for (int rr=0;rr<4;++rr){
            const int row = mt*16 + aq*4 + rr;
            stg32((unsigned*)(part + ((((size_t)mh*64+row)*128 + wgc)*128 + col)),
                  __float_as_uint(acc[j][rr]));
        }
    }
}

// ---------------- the whole model, one persistent kernel ----------------
__global__ __launch_bounds__(kNT, 2) void seq2seq_kernel(
    const void* __restrict__ enc_in_raw, const void* __restrict__ fc1_w_raw,
    const void* __restrict__ fc1_b_raw,  const void* __restrict__ w_ih_raw,
    const void* __restrict__ w_hh_raw,   const void* __restrict__ b_ih_raw,
    const void* __restrict__ b_hh_raw,   const void* __restrict__ fc2_w_raw,
    const void* __restrict__ fc2_b_raw,
    void* __restrict__ out_raw,
    u16* __restrict__ enc_act,           // [50][128][128] bf16
    u16* __restrict__ h_b16,             // kRing x slice-major [128][128][16] bf16
    u16* __restrict__ inp_b16,           // kRing x [128][128] bf16
    float* __restrict__ inp_f32,         // kRing x [128][128] f32
    float* __restrict__ encF,            // [128][128] f32
    float* __restrict__ bias,            // 6*kR + 2*kD f32
    float* __restrict__ part,            // [2][64][128][128] f32 = 8 MB
    int* flags,
    u16* __restrict__ cv_encx, u16* __restrict__ cv_fc2, u16* __restrict__ cv_fc1)
{
    __shared__ __align__(16) u16 smem[33792];   // 64 KB red/pool + 2 KB sH
    __shared__ int sflag;
    u16* sH = smem + 32768;
    const int wg = blockIdx.x, tid = threadIdx.x;
    const int wgc = wg & 127, mrow0 = (wg >> 7) * 64;
    const int lane = tid & 63, wv = tid >> 6, ar = lane & 15, aq = lane >> 4;
    const int gtid = wg * kNT + tid, gstride = kNB * kNT;
    const int dom = (wg >> 7) * 128;            // flag domain base (row half)
    const size_t HS = (size_t)kB*kR;            // u16 elems per h ring slot

    // ---- dtype detect: f32-as-bf16 shows Inf/NaN bit patterns in low halves ----
    {
        const u16* p = (const u16*)enc_in_raw;
        int found = 0;
        for (int i = tid; i < 16384; i += kNT) found |= ((p[i] & 0x7F80) == 0x7F80) ? 1 : 0;
        if (tid == 0) sflag = 0;
        __syncthreads();
        if (found) sflag = 1;
        __syncthreads();
    }
    const bool F32 = (sflag != 0);

    // ---- register-resident recurrent weights (persist all 74 steps) ----
    bf16x8 wB[3][8];   // w_hh[gate][k-chunk]: wave wv covers k in [256*wv,+256)
    bf16x8 wI[3];      // w_ih[gate]: wave wv<4 covers k-chunk 32*wv
    {
        const int w4 = wv & 3;
        if (F32){
            const float* Wh = (const float*)w_hh_raw;
            const float* Wi = (const float*)w_ih_raw;
#pragma unroll
            for (int g=0; g<3; ++g)
#pragma unroll
                for (int c=0; c<8; ++c){
                    size_t o = (size_t)(g*kR + wgc*16 + ar)*kR + 256*wv + 32*c + aq*8;
                    wB[g][c] = pack8(*(const float4*)(Wh+o), *(const float4*)(Wh+o+4));
                }
#pragma unroll
            for (int g=0; g<3; ++g){
                size_t o = (size_t)(g*kR + wgc*16 + ar)*kD + 32*w4 + aq*8;
                wI[g] = pack8(*(const float4*)(Wi+o), *(const float4*)(Wi+o+4));
            }
        } else {
            const u16* Wh = (const u16*)w_hh_raw;
            const u16* Wi = (const u16*)w_ih_raw;
#pragma unroll
            for (int g=0; g<3; ++g)
#pragma unroll
                for (int c=0; c<8; ++c)
                    wB[g][c] = *(const bf16x8*)(Wh + (size_t)(g*kR + wgc*16 + ar)*kR + 256*wv + 32*c + aq*8);
#pragma unroll
            for (int g=0; g<3; ++g)
                wI[g] = *(const bf16x8*)(Wi + (size_t)(g*kR + wgc*16 + ar)*kD + 32*w4 + aq*8);
        }
    }

    // ---- init: conversions + bias + zero h slot 0, all via coherent stores ----
    if (F32) {
        cvt_f32_bf16((const float*)fc2_w_raw, cv_fc2,  (kD*kR)/4,       gtid, gstride);
        cvt_f32_bf16((const float*)fc1_w_raw, cv_fc1,  (kD*kD)/4,       gtid, gstride);
        cvt_f32_bf16((const float*)enc_in_raw,cv_encx, (kB*kSin*kD)/4,  gtid, gstride);
        for (int i = gtid; i < 3*kR; i += gstride) {
            stg32((unsigned*)&bias[i],        __float_as_uint(((const float*)b_ih_raw)[i]));
            stg32((unsigned*)&bias[3*kR + i], __float_as_uint(((const float*)b_hh_raw)[i]));
        }
        for (int i = gtid; i < kD; i += gstride) {
            stg32((unsigned*)&bias[6*kR + i],      __float_as_uint(((const float*)fc1_b_raw)[i]));
            stg32((unsigned*)&bias[6*kR + kD + i], __float_as_uint(((const float*)fc2_b_raw)[i]));
        }
    } else {
        for (int i = gtid; i < 3*kR; i += gstride) {
            stg32((unsigned*)&bias[i],        __float_as_uint(bf2f(((const u16*)b_ih_raw)[i])));
            stg32((unsigned*)&bias[3*kR + i], __float_as_uint(bf2f(((const u16*)b_hh_raw)[i])));
        }
        for (int i = gtid; i < kD; i += gstride) {
            stg32((unsigned*)&bias[6*kR + i],      __float_as_uint(bf2f(((const u16*)fc1_b_raw)[i])));
            stg32((unsigned*)&bias[6*kR + kD + i], __float_as_uint(bf2f(((const u16*)fc2_b_raw)[i])));
        }
    }
    for (int i = gtid; i < (int)((kB*kR)/2); i += gstride) stg32((unsigned*)h_b16 + i, 0u);
    gbar(flags, 1, 0, 4);                // tok 1: global barrier (256 flags)

    const u16* ENCX = F32 ? cv_encx : (const u16*)enc_in_raw;
    const u16* WF2  = F32 ? cv_fc2  : (const u16*)fc2_w_raw;
    const u16* WF1  = F32 ? cv_fc1  : (const u16*)fc1_w_raw;

    // ---- per-thread constant preloads (first-touch after global barrier) ----
    float4 b4;   // gate biases for this thread's (hc)
    {
        const int hc = wgc*16 + ar;
        b4.x = aldf(&bias[hc])      + aldf(&bias[3*kR+hc]);
        b4.y = aldf(&bias[kR+hc])   + aldf(&bias[4*kR+hc]);
        b4.z = aldf(&bias[2*kR+hc]);
        b4.w = aldf(&bias[5*kR+hc]);
    }
    bf16x8 wF2[4];   // fc2_w[(nh*4+j)*16+ar][wgc*16 + aq*8 ..+8], reg-resident
    {
        const int nh = wv>>2;
#pragma unroll
        for (int j=0;j<4;++j){
            if (aq < 2)
                wF2[j] = ald128bf(WF2 + (size_t)((nh*4+j)*16+ar)*kR + wgc*16 + aq*8);
            else {
#pragma unroll
                for (int i=0;i<8;++i) wF2[j][i] = (__bf16)0.f;
            }
        }
    }
    const float fc2b = aldf(&bias[6*kR + kD + (wg&1)*64 + (tid&63)]);
    float hprev[4] = {0.f, 0.f, 0.f, 0.f};

    // ---- fc1: blocks wgc<50 handle t=wgc ----
    if (wgc < kSin) {
        const int g = wv>>2, mt = wv&3;
        const f32x4 zz = {0.f,0.f,0.f,0.f};
        f32x4 ae[4] = {zz,zz,zz,zz};
        small_gemm<8,4>(ENCX + ((size_t)mrow0*kSin + wgc)*kD, kSin*kD, WF1, kD, ae, smem);
#pragma unroll
        for (int jt=0; jt<8; ++jt){
            if ((jt&1) != g) continue;
            int col = jt*16 + ar;
            float fb = aldf(&bias[6*kR + col]);
#pragma unroll
            for (int rr=0; rr<4; ++rr){
                int m = mrow0 + mt*16 + aq*4 + rr;
                float v = ae[jt>>1][rr] + fb;
                u16 hb = f2bf(v);
                unsigned other = (unsigned)__shfl_xor((int)(unsigned)hb, 1);
                if (!(ar&1))
                    stg32((unsigned*)(enc_act + ((size_t)wgc*kB + m)*kD + col),
                          (unsigned)hb | (other<<16));
                if (wgc == kSin-1)
                    stg32((unsigned*)(encF + (size_t)m*kD + col), __float_as_uint(v));
            }
        }
    }
    gbar(flags, 2, dom, 2);              // tok 2: half-domain barrier

    // ---- encoder: 49 GRU steps; h-token H_t = t+3 published in-barrier ----
    for (int t = 0; t < kSin-1; ++t) {
        gru_phase_flag(h_b16 + (size_t)(t & 7)*HS, h_b16 + (size_t)((t+1) & 7)*HS,
                       enc_act + (size_t)t*kB*kD, wB, wI, b4, hprev, wgc, mrow0, smem, sH,
                       flags, (t==0 ? 0 : t+2), 0, dom,
                       (t > 0) && ((t & 7) == 0), t+3);
    }

    // ---- decoder: 25 steps; tokens per d: HA=52+3d, PB=53+3d, XB=54+3d ----
    const u16*   ib  = enc_act + (size_t)(kSin-1)*kB*kD;
    const float* ifp = encF;
    const int mh = wg >> 7;
    for (int d = 0; d < kT; ++d) {
        const int g = 49 + d;
        // phase A: GRU; h-ready token published BEFORE fc2_partial so step
        // d+1's producers-wait is not delayed by the fc2 stores.
        gru_phase_flag(h_b16 + (size_t)(g & 7)*HS, h_b16 + (size_t)((g+1) & 7)*HS,
                       ib, wB, wI, b4, hprev, wgc, mrow0, smem, sH,
                       flags, (d==0 ? 51 : 49+3*d), (d==0 ? 0 : 51+3*d), dom,
                       (g & 7) == 0, 52+3*d);
        fc2_partial(sH, wF2, wgc, mh, part);
        arrive(flags, 53+3*d);           // PB_d: parts ready

        // phase B: reduce 128 slice-partials -> out + next x
        u16*   nib = inp_b16 + (size_t)(d & 7)*kB*kD;
        float* nif = inp_f32 + (size_t)(d & 7)*kB*kD;
        wait128(flags, 53+3*d, dom);     // all waves: wait this half's parts
        {
            const int row = wg >> 1, ch = wg & 1;
            const int mh2 = row >> 6, rl = row & 63;
            const float* pr = part + (size_t)((mh2*64 + rl)*128)*128;
            const int cl = tid & 63, sg = tid >> 6;
            float s = 0.f;
#pragma unroll
            for (int j=0;j<16;++j) s += aldf(&pr[(size_t)(sg*16+j)*128 + ch*64 + cl]);
            float* red2 = (float*)smem;
            red2[sg*64 + cl] = s;
            __syncthreads();
            if (tid < 64){
                float t2 = 0.f;
#pragma unroll
                for (int g2=0; g2<8; ++g2) t2 += red2[g2*64 + tid];
                const int colg = ch*64 + tid;
                const float o = t2 + fc2b + aldf(&ifp[(size_t)row*kD + colg]);
                const size_t ob = ((size_t)row*kT + d)*kD + colg;
                if (F32) ((float*)out_raw)[ob] = o;
                else     ((u16*)out_raw)[ob]   = f2bf(o);
                stg32((unsigned*)(nif + (size_t)row*kD + colg), __float_as_uint(o));
                u16 hb = f2bf(o);
                unsigned other = (unsigned)__shfl_xor((int)(unsigned)hb, 1);
                if (!(tid&1))
                    stg32((unsigned*)(nib + (size_t)row*kD + colg), (unsigned)hb | (other<<16));
            }
        }
        arrive(flags, 54+3*d);           // XB_d: next-x ready
        ib = nib; ifp = nif;
    }
}

// ---------------- host launcher ----------------
extern "C" void kernel_launch(void* const* d_in, const int* in_sizes, int n_in,
                              void* d_out, int out_size, void* d_ws, size_t ws_size,
                              hipStream_t stream)
{
    size_t off = 0;
    char* ws = (char*)d_ws;
    auto alloc = [&](size_t bytes) -> char* {
        char* p = ws + off;
        off = (off + bytes + 255) & ~(size_t)255;
        return p;
    };
    u16*   enc_act = (u16*)alloc((size_t)kSin*kB*kD*2);
    u16*   h_b16   = (u16*)alloc((size_t)kRing*kB*kR*2);         // 4 MB ring
    u16*   inp_b16 = (u16*)alloc((size_t)kRing*kB*kD*2);
    float* inp_f32 = (float*)alloc((size_t)kRing*kB*kD*4);
    float* encF    = (float*)alloc((size_t)kB*kD*4);
    float* bias    = (float*)alloc((size_t)(6*kR + 2*kD)*4);
    float* part    = (float*)alloc((size_t)2*64*128*128*4);      // 8 MB
    int*   flags   = (int*)alloc((size_t)kNB*16*4);              // 1 flag / 64B line
    u16*   cv_encx = (u16*)alloc((size_t)kB*kSin*kD*2);
    u16*   cv_fc2  = (u16*)alloc((size_t)kD*kR*2);
    u16*   cv_fc1  = (u16*)alloc((size_t)kD*kD*2);
    (void)ws_size; (void)in_sizes; (void)n_in; (void)out_size;

    seq2seq_kernel<<<dim3(kNB), dim3(kNT), 0, stream>>>(
        d_in[0], d_in[2], d_in[3], d_in[4], d_in[5], d_in[6], d_in[7], d_in[8], d_in[9],
        d_out,
        enc_act, h_b16, inp_b16, inp_f32, encF, bias, part, flags,
        cv_encx, cv_fc2, cv_fc1);
}